// Round 4
// baseline (547.665 us; speedup 1.0000x reference)
//
#include <hip/hip_runtime.h>

#define NUM_ENT 64
#define DIM_ENT 8
#define NHID    64
#define NEMB    256
#define BATCH   1024
#define NUM_REL 2016
#define KTOT    (NUM_REL * NHID)   // 129024

typedef __attribute__((ext_vector_type(8))) short bf16x8;
typedef __attribute__((ext_vector_type(4))) float f32x4;

__device__ __forceinline__ unsigned short f2bf(float f) {
    union { float f; unsigned u; } v; v.f = f;
    unsigned r = v.u + 0x7FFF + ((v.u >> 16) & 1);   // RNE
    return (unsigned short)(r >> 16);
}

// ---------------------------------------------------------------------------
// prep: ctx fp32 [1024,512] -> bf16 (coalesced)
// ---------------------------------------------------------------------------
__global__ void prep_ctx_kernel(const float* __restrict__ ctx,
                                unsigned short* __restrict__ ctxb) {
    const int id = blockIdx.x * 256 + threadIdx.x;
    const float4 a = ((const float4*)ctx)[id * 2];
    const float4 b = ((const float4*)ctx)[id * 2 + 1];
    bf16x8 v;
    v[0] = (short)f2bf(a.x); v[1] = (short)f2bf(a.y);
    v[2] = (short)f2bf(a.z); v[3] = (short)f2bf(a.w);
    v[4] = (short)f2bf(b.x); v[5] = (short)f2bf(b.y);
    v[6] = (short)f2bf(b.z); v[7] = (short)f2bf(b.w);
    *(bf16x8*)(ctxb + (size_t)id * 8) = v;
}

// ---------------------------------------------------------------------------
// prep: Wfc fp32 [129024,256] -> wt bf16 [256][129024] (LDS-tiled transpose,
// coalesced read AND write; one 64-row k-tile = one relation per block)
// ---------------------------------------------------------------------------
__global__ __launch_bounds__(512) void prep_wfcT_kernel(
    const float* __restrict__ Wfc, unsigned short* __restrict__ wt) {
    __shared__ unsigned short tile[64 * 260];          // pad 256->260 (bank stride 2)
    const int g = blockIdx.x;                          // 0..2015
    const int t = threadIdx.x;
    const float4* __restrict__ src = (const float4*)(Wfc + (size_t)g * 64 * NEMB);
#pragma unroll
    for (int i = 0; i < 8; ++i) {
        const int f4 = t + i * 512;                    // float4 index within tile
        const float4 v = src[f4];
        const int f = f4 * 4, k = f >> 8, n = f & 255;
        ushort4 u;
        u.x = f2bf(v.x); u.y = f2bf(v.y); u.z = f2bf(v.z); u.w = f2bf(v.w);
        *(ushort4*)&tile[k * 260 + n] = u;
    }
    __syncthreads();
    const int n = t & 255, half = t >> 8;
    unsigned short* __restrict__ dst = wt + (size_t)n * KTOT + g * 64 + half * 32;
#pragma unroll
    for (int c = 0; c < 8; ++c) {
        const int k0 = half * 32 + c * 4;
        ushort4 u;
        u.x = tile[(k0 + 0) * 260 + n];
        u.y = tile[(k0 + 1) * 260 + n];
        u.z = tile[(k0 + 2) * 260 + n];
        u.w = tile[(k0 + 3) * 260 + n];
        *(ushort4*)(dst + c * 4) = u;
    }
}

// ---------------------------------------------------------------------------
// fused3: per relation r -> h=relu(pairs@Wrel+brel) in LDS (bf16, swizzled),
// acc += h @ Wfc via MFMA with B from transposed-bf16 wt, software-pipelined
// loads across raw s_barrier (vmcnt never drained in loop).
// ---------------------------------------------------------------------------
#define BARRIER() do { \
    asm volatile("s_waitcnt lgkmcnt(0)" ::: "memory"); \
    __builtin_amdgcn_s_barrier(); \
    __builtin_amdgcn_sched_barrier(0); \
} while (0)

template<bool ATOMIC>
__global__ __launch_bounds__(512, 4) void fused3_kernel(
    const unsigned short* __restrict__ ctxb,   // [1024,512] bf16
    const float*          __restrict__ Wrel,   // [16,64]
    const float*          __restrict__ brel,   // [64]
    const unsigned short* __restrict__ wt,     // [256][129024] bf16
    float*                __restrict__ outp)   // partial[64][1024,256] or out
{
    const int bid = blockIdx.x;
    const int mb  = (bid >> 3) & 7;
    const int ks  = (bid & 7) + 8 * (bid >> 6);       // slice-sharers on one XCD
    const int start = (ks < 32) ? ks * 32 : 1024 + (ks - 32) * 31;
    const int cnt   = (ks < 32) ? 32 : 31;

    const int tid = threadIdx.x;
    const int w   = tid >> 6;
    const int l   = tid & 63;
    const int l15 = l & 15;
    const int kb  = l >> 4;

    __shared__ unsigned short h_lds[2][128 * NHID];
    __shared__ int pair_i[32], pair_j[32];

    if (tid < cnt) {
        int rem = start + tid;
        int i = 0;
        while (rem >= (NUM_ENT - 1 - i)) { rem -= (NUM_ENT - 1 - i); ++i; }
        pair_i[tid] = i;
        pair_j[tid] = i + 1 + rem;
    }

    // Wrel^T A-frag (swapped phase-1); padding row k==16 carries the bias.
    bf16x8 bw[4];
#pragma unroll
    for (int ns = 0; ns < 4; ++ns) {
#pragma unroll
        for (int e = 0; e < 8; ++e) {
            const int k = kb * 8 + e;
            float v = 0.f;
            if (k < 16)       v = Wrel[k * NHID + ns * 16 + l15];
            else if (k == 16) v = brel[ns * 16 + l15];
            bw[ns][e] = (short)f2bf(v);
        }
    }

    __syncthreads();   // pair table

    f32x4 acc[8][2];
#pragma unroll
    for (int m = 0; m < 8; ++m)
#pragma unroll
        for (int n = 0; n < 2; ++n) acc[m][n] = (f32x4){0.f, 0.f, 0.f, 0.f};

    const int rw = w * 16 + l15;   // batch-row this lane serves in phase 1
    const unsigned short* __restrict__ ctx_row =
        ctxb + (size_t)(mb * 128 + rw) * (NUM_ENT * DIM_ENT);
    const unsigned short* __restrict__ wt_lane =
        wt + (size_t)(w * 32 + l15) * KTOT + kb * 8;

    auto LOADB = [&](int g, bf16x8 (&bb)[2][2]) {
        const unsigned short* __restrict__ p = wt_lane + g * 64;
        bb[0][0] = *(const bf16x8*)(p);
        bb[0][1] = *(const bf16x8*)(p + (size_t)16 * KTOT);
        bb[1][0] = *(const bf16x8*)(p + 32);
        bb[1][1] = *(const bf16x8*)(p + (size_t)16 * KTOT + 32);
    };

    auto PHASE1 = [&](int r, unsigned short* hb) {
        bf16x8 ah = {0, 0, 0, 0, 0, 0, 0, 0};
        if (kb < 2) {
            const int ent = (kb == 0) ? pair_i[r] : pair_j[r];
            ah = *(const bf16x8*)(ctx_row + ent * DIM_ENT);
        } else if (kb == 2) {
            ah[0] = (short)0x3F80;   // 1.0 -> bias row (k==16)
        }
#pragma unroll
        for (int ns = 0; ns < 4; ++ns) {
            f32x4 c = {0.f, 0.f, 0.f, 0.f};
            c = __builtin_amdgcn_mfma_f32_16x16x32_bf16(bw[ns], ah, c, 0, 0, 0);
            // D = h^T: lane holds hid = ns*16 + kb*4 + reg for batch-row rw
            ushort4 u;
            u.x = f2bf(fmaxf(c[0], 0.f));
            u.y = f2bf(fmaxf(c[1], 0.f));
            u.z = f2bf(fmaxf(c[2], 0.f));
            u.w = f2bf(fmaxf(c[3], 0.f));
            int byte = (rw * NHID + ns * 16 + kb * 4) * 2;
            byte ^= ((rw & 7) << 4);
            *(ushort4*)((char*)hb + byte) = u;   // ds_write_b64
        }
    };

    auto PHASE2 = [&](const bf16x8 (&bb)[2][2], const unsigned short* hb) {
#pragma unroll
        for (int kh = 0; kh < 2; ++kh)
#pragma unroll
            for (int m = 0; m < 8; ++m) {
                const int rr = m * 16 + l15;
                int byte = (rr * NHID + kh * 32 + kb * 8) * 2;
                byte ^= ((rr & 7) << 4);
                const bf16x8 aa = *(const bf16x8*)((const char*)hb + byte);
                acc[m][0] = __builtin_amdgcn_mfma_f32_16x16x32_bf16(aa, bb[kh][0], acc[m][0], 0, 0, 0);
                acc[m][1] = __builtin_amdgcn_mfma_f32_16x16x32_bf16(aa, bb[kh][1], acc[m][1], 0, 0, 0);
            }
    };

    bf16x8 bbA[2][2], bbB[2][2];
    LOADB(start, bbA);
    int r = 0;
    while (r + 2 <= cnt) {
        LOADB(start + r + 1, bbB);           // in flight across next barrier
        PHASE1(r, h_lds[0]);
        BARRIER();
        PHASE2(bbA, h_lds[0]);
        if (r + 2 < cnt) LOADB(start + r + 2, bbA);
        PHASE1(r + 1, h_lds[1]);
        BARRIER();
        PHASE2(bbB, h_lds[1]);
        r += 2;
    }
    if (r < cnt) {                            // odd tail (cnt==31)
        PHASE1(r, h_lds[0]);
        BARRIER();
        PHASE2(bbA, h_lds[0]);
    }

    float* __restrict__ dst = ATOMIC ? outp : (outp + (size_t)ks * BATCH * NEMB);
#pragma unroll
    for (int m = 0; m < 8; ++m)
#pragma unroll
        for (int ns = 0; ns < 2; ++ns)
#pragma unroll
            for (int reg = 0; reg < 4; ++reg) {
                const int row = mb * 128 + m * 16 + kb * 4 + reg;
                const int col = w * 32 + ns * 16 + l15;
                if (ATOMIC) atomicAdd(&dst[(size_t)row * NEMB + col], acc[m][ns][reg]);
                else        dst[(size_t)row * NEMB + col] = acc[m][ns][reg];
            }
}

// partial[64][1024,256] -> out = relu(sum + bias)
__global__ void reduce_kernel(const float* __restrict__ part,
                              const float* __restrict__ bfc,
                              float* __restrict__ out) {
    const int i = blockIdx.x * 256 + threadIdx.x;
    float4 s = {0.f, 0.f, 0.f, 0.f};
    const float4* __restrict__ p = (const float4*)part + i;
#pragma unroll 16
    for (int ks = 0; ks < 64; ++ks) {
        const float4 v = p[(size_t)ks * (BATCH * NEMB / 4)];
        s.x += v.x; s.y += v.y; s.z += v.z; s.w += v.w;
    }
    const int c = (i * 4) & (NEMB - 1);
    s.x = fmaxf(s.x + bfc[c + 0], 0.f);
    s.y = fmaxf(s.y + bfc[c + 1], 0.f);
    s.z = fmaxf(s.z + bfc[c + 2], 0.f);
    s.w = fmaxf(s.w + bfc[c + 3], 0.f);
    ((float4*)out)[i] = s;
}

__global__ void bias_relu_kernel(float* __restrict__ out, const float* __restrict__ bfc) {
    const int i = blockIdx.x * 256 + threadIdx.x;
    float4 v = ((float4*)out)[i];
    const int c = (i * 4) & (NEMB - 1);
    v.x = fmaxf(v.x + bfc[c + 0], 0.f);
    v.y = fmaxf(v.y + bfc[c + 1], 0.f);
    v.z = fmaxf(v.z + bfc[c + 2], 0.f);
    v.w = fmaxf(v.w + bfc[c + 3], 0.f);
    ((float4*)out)[i] = v;
}

// ---------------------------------------------------------------------------
// Legacy fallback (round-2 kernel, known-pass) if d_ws is too small.
// ---------------------------------------------------------------------------
__global__ __launch_bounds__(512, 2) void fused_legacy_kernel(
    const float* __restrict__ ctx, const float* __restrict__ Wrel,
    const float* __restrict__ brel, const float* __restrict__ Wfc,
    float* __restrict__ out)
{
    const int bid = blockIdx.x;
    const int ks  = bid & 31;
    const int mb  = bid >> 5;
    const int tid = threadIdx.x;
    const int w   = tid >> 6;
    const int l   = tid & 63;
    const int l15 = l & 15;
    const int kb  = l >> 4;

    __shared__ unsigned short h_lds[2][128 * NHID];
    __shared__ int pair_i[63], pair_j[63];

    if (tid < 63) {
        int rem = ks * 63 + tid;
        int i = 0;
        while (rem >= (NUM_ENT - 1 - i)) { rem -= (NUM_ENT - 1 - i); ++i; }
        pair_i[tid] = i;
        pair_j[tid] = i + 1 + rem;
    }

    bf16x8 bw[4];
    float  brl[4];
#pragma unroll
    for (int ns = 0; ns < 4; ++ns) {
        const int n = l15 + 16 * ns;
#pragma unroll
        for (int e = 0; e < 8; ++e) {
            const int k = kb * 8 + e;
            bw[ns][e] = (short)f2bf((k < 16) ? Wrel[k * NHID + n] : 0.f);
        }
        brl[ns] = brel[n];
    }
    __syncthreads();

    f32x4 acc[8][2];
#pragma unroll
    for (int m = 0; m < 8; ++m)
#pragma unroll
        for (int n = 0; n < 2; ++n) acc[m][n] = (f32x4){0.f, 0.f, 0.f, 0.f};

    const int row_h = mb * 128 + w * 16 + l15;
    const float* __restrict__ ctx_row = ctx + (size_t)row_h * (NUM_ENT * DIM_ENT);

    for (int r = 0; r < 63; ++r) {
        unsigned short* __restrict__ hb = &h_lds[r & 1][0];
        bf16x8 ah = {0, 0, 0, 0, 0, 0, 0, 0};
        if (kb < 2) {
            const int ent = (kb == 0) ? pair_i[r] : pair_j[r];
            const float4 v0 = *(const float4*)(ctx_row + ent * DIM_ENT);
            const float4 v1 = *(const float4*)(ctx_row + ent * DIM_ENT + 4);
            ah[0] = (short)f2bf(v0.x); ah[1] = (short)f2bf(v0.y);
            ah[2] = (short)f2bf(v0.z); ah[3] = (short)f2bf(v0.w);
            ah[4] = (short)f2bf(v1.x); ah[5] = (short)f2bf(v1.y);
            ah[6] = (short)f2bf(v1.z); ah[7] = (short)f2bf(v1.w);
        }
#pragma unroll
        for (int ns = 0; ns < 4; ++ns) {
            f32x4 c = {0.f, 0.f, 0.f, 0.f};
            c = __builtin_amdgcn_mfma_f32_16x16x32_bf16(ah, bw[ns], c, 0, 0, 0);
#pragma unroll
            for (int reg = 0; reg < 4; ++reg) {
                float hv = c[reg] + brl[ns];
                hv = hv > 0.f ? hv : 0.f;
                const int rr = w * 16 + kb * 4 + reg;
                const int cc = l15 + 16 * ns;
                int byte = (rr * NHID + cc) * 2;
                byte ^= ((rr & 7) << 4);
                *(unsigned short*)((char*)hb + byte) = f2bf(hv);
            }
        }
        __syncthreads();

        const float* __restrict__ wf = Wfc + (size_t)(ks * 63 + r) * NHID * NEMB;
#pragma unroll
        for (int kh = 0; kh < 2; ++kh) {
            bf16x8 bb[2];
#pragma unroll
            for (int ns = 0; ns < 2; ++ns) {
                const int n = w * 32 + ns * 16 + l15;
                const float* __restrict__ col = wf + (size_t)(kh * 32 + kb * 8) * NEMB + n;
#pragma unroll
                for (int e = 0; e < 8; ++e) bb[ns][e] = (short)f2bf(col[(size_t)e * NEMB]);
            }
#pragma unroll
            for (int m = 0; m < 8; ++m) {
                const int rr = m * 16 + l15;
                int byte = (rr * NHID + kh * 32 + kb * 8) * 2;
                byte ^= ((rr & 7) << 4);
                const bf16x8 aa = *(const bf16x8*)((const char*)hb + byte);
                acc[m][0] = __builtin_amdgcn_mfma_f32_16x16x32_bf16(aa, bb[0], acc[m][0], 0, 0, 0);
                acc[m][1] = __builtin_amdgcn_mfma_f32_16x16x32_bf16(aa, bb[1], acc[m][1], 0, 0, 0);
            }
        }
    }
#pragma unroll
    for (int m = 0; m < 8; ++m)
#pragma unroll
        for (int ns = 0; ns < 2; ++ns)
#pragma unroll
            for (int reg = 0; reg < 4; ++reg) {
                const int row = mb * 128 + m * 16 + kb * 4 + reg;
                const int col = w * 32 + ns * 16 + l15;
                atomicAdd(&out[(size_t)row * NEMB + col], acc[m][ns][reg]);
            }
}

extern "C" void kernel_launch(void* const* d_in, const int* in_sizes, int n_in,
                              void* d_out, int out_size, void* d_ws, size_t ws_size,
                              hipStream_t stream) {
    const float* ctx  = (const float*)d_in[0];
    const float* Wrel = (const float*)d_in[1];
    const float* brel = (const float*)d_in[2];
    const float* Wfc  = (const float*)d_in[3];
    const float* bfc  = (const float*)d_in[4];
    float* out = (float*)d_out;

    const size_t CTXB = (size_t)BATCH * NUM_ENT * DIM_ENT * 2;   // 1 MiB
    const size_t WFCB = (size_t)KTOT * NEMB * 2;                 // 63 MiB
    const size_t PART = (size_t)64 * BATCH * NEMB * 4;           // 64 MiB
    unsigned short* ctxb = (unsigned short*)d_ws;
    unsigned short* wfct = (unsigned short*)((char*)d_ws + CTXB);
    float*          part = (float*)((char*)d_ws + CTXB + WFCB);

    if (ws_size >= CTXB + WFCB + PART) {
        prep_ctx_kernel<<<256, 256, 0, stream>>>(ctx, ctxb);
        prep_wfcT_kernel<<<NUM_REL, 512, 0, stream>>>(Wfc, wfct);
        fused3_kernel<false><<<512, 512, 0, stream>>>(ctxb, Wrel, brel, wfct, part);
        reduce_kernel<<<256, 256, 0, stream>>>(part, bfc, out);
    } else if (ws_size >= CTXB + WFCB) {
        prep_ctx_kernel<<<256, 256, 0, stream>>>(ctx, ctxb);
        prep_wfcT_kernel<<<NUM_REL, 512, 0, stream>>>(Wfc, wfct);
        hipMemsetAsync(out, 0, (size_t)BATCH * NEMB * sizeof(float), stream);
        fused3_kernel<true><<<512, 512, 0, stream>>>(ctxb, Wrel, brel, wfct, out);
        bias_relu_kernel<<<(BATCH * NEMB / 4) / 256, 256, 0, stream>>>(out, bfc);
    } else {
        hipMemsetAsync(out, 0, (size_t)BATCH * NEMB * sizeof(float), stream);
        fused_legacy_kernel<<<256, 512, 0, stream>>>(ctx, Wrel, brel, Wfc, out);
        bias_relu_kernel<<<(BATCH * NEMB / 4) / 256, 256, 0, stream>>>(out, bfc);
    }
}

// Round 5
// 506.138 us; speedup vs baseline: 1.0820x; 1.0820x over previous
//
#include <hip/hip_runtime.h>

#define NUM_ENT 64
#define DIM_ENT 8
#define NHID    64
#define NEMB    256
#define BATCH   1024
#define NUM_REL 2016
#define KTOT    (NUM_REL * NHID)   // 129024

typedef __attribute__((ext_vector_type(8))) short bf16x8;
typedef __attribute__((ext_vector_type(4))) float f32x4;

__device__ __forceinline__ unsigned short f2bf(float f) {
    union { float f; unsigned u; } v; v.f = f;
    unsigned r = v.u + 0x7FFF + ((v.u >> 16) & 1);   // RNE
    return (unsigned short)(r >> 16);
}

// ---------------------------------------------------------------------------
// prep: ctx fp32 [1024,512] -> bf16 (coalesced)
// ---------------------------------------------------------------------------
__global__ void prep_ctx_kernel(const float* __restrict__ ctx,
                                unsigned short* __restrict__ ctxb) {
    const int id = blockIdx.x * 256 + threadIdx.x;
    const float4 a = ((const float4*)ctx)[id * 2];
    const float4 b = ((const float4*)ctx)[id * 2 + 1];
    bf16x8 v;
    v[0] = (short)f2bf(a.x); v[1] = (short)f2bf(a.y);
    v[2] = (short)f2bf(a.z); v[3] = (short)f2bf(a.w);
    v[4] = (short)f2bf(b.x); v[5] = (short)f2bf(b.y);
    v[6] = (short)f2bf(b.z); v[7] = (short)f2bf(b.w);
    *(bf16x8*)(ctxb + (size_t)id * 8) = v;
}

// ---------------------------------------------------------------------------
// prep: Wfc fp32 [129024,256] -> frag-linear bf16, one relation per block.
//   u16 index = ((g*2+kh)*16 + fid)*512 + l*8 + e
//     holds Wfc[g*64 + kh*32 + (l>>4)*8 + e][(fid>>1)*32 + (fid&1)*16 + (l&15)]
// Relation-contiguous 32KB chunks -> streaming-friendly L2 (no set aliasing).
// Coalesced global reads (float4) and writes (64B/thread) via LDS tile.
// ---------------------------------------------------------------------------
__global__ __launch_bounds__(512) void prep_wfc2_kernel(
    const float* __restrict__ Wfc, unsigned short* __restrict__ wfcb) {
    __shared__ unsigned short tile[64 * 260];          // pad 256->260
    const int g = blockIdx.x;                          // 0..2015
    const int t = threadIdx.x;
    const float4* __restrict__ src = (const float4*)(Wfc + (size_t)g * 64 * NEMB);
#pragma unroll
    for (int i = 0; i < 8; ++i) {
        const int f4 = t + i * 512;                    // 4096 float4 in tile
        const float4 v = src[f4];
        const int f = f4 * 4, k = f >> 8, n = f & 255;
        ushort4 u;
        u.x = f2bf(v.x); u.y = f2bf(v.y); u.z = f2bf(v.z); u.w = f2bf(v.w);
        *(ushort4*)&tile[k * 260 + n] = u;
    }
    __syncthreads();
    unsigned short* __restrict__ dst = wfcb + (size_t)g * 16384 + (size_t)t * 32;
#pragma unroll
    for (int c = 0; c < 4; ++c) {
        const int s   = t * 4 + c;                     // slot 0..2047
        const int l   = s & 63;
        const int fid = (s >> 6) & 15;
        const int kh  = s >> 10;
        const int n   = (fid >> 1) * 32 + (fid & 1) * 16 + (l & 15);
        const int k0  = kh * 32 + ((l >> 4) << 3);
        bf16x8 v;
#pragma unroll
        for (int e = 0; e < 8; ++e) v[e] = (short)tile[(k0 + e) * 260 + n];
        *(bf16x8*)(dst + c * 8) = v;                   // 64B contiguous per thread
    }
}

// ---------------------------------------------------------------------------
// fused4: frag-linear B (L2-friendly) + pipelined raw-barrier loop
// (lgkmcnt-only at barrier; B-loads stay in flight across it).
// ---------------------------------------------------------------------------
#define BARRIER() do { \
    asm volatile("s_waitcnt lgkmcnt(0)" ::: "memory"); \
    __builtin_amdgcn_s_barrier(); \
    __builtin_amdgcn_sched_barrier(0); \
} while (0)

template<bool ATOMIC>
__global__ __launch_bounds__(512, 4) void fused4_kernel(
    const unsigned short* __restrict__ ctxb,   // [1024,512] bf16
    const float*          __restrict__ Wrel,   // [16,64]
    const float*          __restrict__ brel,   // [64]
    const unsigned short* __restrict__ wfcb,   // frag-linear bf16
    float*                __restrict__ outp)   // partial[64][1024,256] or out
{
    const int bid = blockIdx.x;
    const int mb  = (bid >> 3) & 7;
    const int ks  = (bid & 7) + 8 * (bid >> 6);       // slice-sharers on one XCD
    const int start = (ks < 32) ? ks * 32 : 1024 + (ks - 32) * 31;
    const int cnt   = (ks < 32) ? 32 : 31;

    const int tid = threadIdx.x;
    const int w   = tid >> 6;
    const int l   = tid & 63;
    const int l15 = l & 15;
    const int kb  = l >> 4;

    __shared__ unsigned short h_lds[2][128 * NHID];
    __shared__ int pair_i[32], pair_j[32];

    if (tid < cnt) {
        int rem = start + tid;
        int i = 0;
        while (rem >= (NUM_ENT - 1 - i)) { rem -= (NUM_ENT - 1 - i); ++i; }
        pair_i[tid] = i;
        pair_j[tid] = i + 1 + rem;
    }

    // Wrel^T A-frag (swapped phase-1); padding row k==16 carries the bias.
    bf16x8 bw[4];
#pragma unroll
    for (int ns = 0; ns < 4; ++ns) {
#pragma unroll
        for (int e = 0; e < 8; ++e) {
            const int k = kb * 8 + e;
            float v = 0.f;
            if (k < 16)       v = Wrel[k * NHID + ns * 16 + l15];
            else if (k == 16) v = brel[ns * 16 + l15];
            bw[ns][e] = (short)f2bf(v);
        }
    }

    __syncthreads();   // pair table

    f32x4 acc[8][2];
#pragma unroll
    for (int m = 0; m < 8; ++m)
#pragma unroll
        for (int n = 0; n < 2; ++n) acc[m][n] = (f32x4){0.f, 0.f, 0.f, 0.f};

    const int rw = w * 16 + l15;   // batch-row this lane serves in phase 1
    const unsigned short* __restrict__ ctx_row =
        ctxb + (size_t)(mb * 128 + rw) * (NUM_ENT * DIM_ENT);
    const unsigned short* __restrict__ wb_lane =
        wfcb + (size_t)(w * 2) * 512 + (size_t)l * 8;

    auto LOADB = [&](int g, bf16x8 (&bb)[2][2]) {
        const unsigned short* __restrict__ p = wb_lane + (size_t)g * 16384;
        bb[0][0] = *(const bf16x8*)(p);
        bb[0][1] = *(const bf16x8*)(p + 512);
        bb[1][0] = *(const bf16x8*)(p + 8192);
        bb[1][1] = *(const bf16x8*)(p + 8192 + 512);
    };

    auto PHASE1 = [&](int r, unsigned short* hb) {
        bf16x8 ah = {0, 0, 0, 0, 0, 0, 0, 0};
        if (kb < 2) {
            const int ent = (kb == 0) ? pair_i[r] : pair_j[r];
            ah = *(const bf16x8*)(ctx_row + ent * DIM_ENT);
        } else if (kb == 2) {
            ah[0] = (short)0x3F80;   // 1.0 -> bias row (k==16)
        }
#pragma unroll
        for (int ns = 0; ns < 4; ++ns) {
            f32x4 c = {0.f, 0.f, 0.f, 0.f};
            c = __builtin_amdgcn_mfma_f32_16x16x32_bf16(bw[ns], ah, c, 0, 0, 0);
            // D = h^T: lane holds hid = ns*16 + kb*4 + reg for batch-row rw
            ushort4 u;
            u.x = f2bf(fmaxf(c[0], 0.f));
            u.y = f2bf(fmaxf(c[1], 0.f));
            u.z = f2bf(fmaxf(c[2], 0.f));
            u.w = f2bf(fmaxf(c[3], 0.f));
            int byte = (rw * NHID + ns * 16 + kb * 4) * 2;
            byte ^= ((rw & 7) << 4);
            *(ushort4*)((char*)hb + byte) = u;   // ds_write_b64
        }
    };

    auto PHASE2 = [&](const bf16x8 (&bb)[2][2], const unsigned short* hb) {
#pragma unroll
        for (int kh = 0; kh < 2; ++kh)
#pragma unroll
            for (int m = 0; m < 8; ++m) {
                const int rr = m * 16 + l15;
                int byte = (rr * NHID + kh * 32 + kb * 8) * 2;
                byte ^= ((rr & 7) << 4);
                const bf16x8 aa = *(const bf16x8*)((const char*)hb + byte);
                acc[m][0] = __builtin_amdgcn_mfma_f32_16x16x32_bf16(aa, bb[kh][0], acc[m][0], 0, 0, 0);
                acc[m][1] = __builtin_amdgcn_mfma_f32_16x16x32_bf16(aa, bb[kh][1], acc[m][1], 0, 0, 0);
            }
    };

    bf16x8 bbA[2][2], bbB[2][2];
    LOADB(start, bbA);
    int r = 0;
    while (r + 2 <= cnt) {
        LOADB(start + r + 1, bbB);           // in flight across next barrier
        PHASE1(r, h_lds[0]);
        BARRIER();
        PHASE2(bbA, h_lds[0]);
        if (r + 2 < cnt) LOADB(start + r + 2, bbA);
        PHASE1(r + 1, h_lds[1]);
        BARRIER();
        PHASE2(bbB, h_lds[1]);
        r += 2;
    }
    if (r < cnt) {                            // odd tail (cnt==31)
        PHASE1(r, h_lds[0]);
        BARRIER();
        PHASE2(bbA, h_lds[0]);
    }

    float* __restrict__ dst = ATOMIC ? outp : (outp + (size_t)ks * BATCH * NEMB);
#pragma unroll
    for (int m = 0; m < 8; ++m)
#pragma unroll
        for (int ns = 0; ns < 2; ++ns)
#pragma unroll
            for (int reg = 0; reg < 4; ++reg) {
                const int row = mb * 128 + m * 16 + kb * 4 + reg;
                const int col = w * 32 + ns * 16 + l15;
                if (ATOMIC) atomicAdd(&dst[(size_t)row * NEMB + col], acc[m][ns][reg]);
                else        dst[(size_t)row * NEMB + col] = acc[m][ns][reg];
            }
}

// partial[64][1024,256] -> out = relu(sum + bias)
__global__ void reduce_kernel(const float* __restrict__ part,
                              const float* __restrict__ bfc,
                              float* __restrict__ out) {
    const int i = blockIdx.x * 256 + threadIdx.x;
    float4 s = {0.f, 0.f, 0.f, 0.f};
    const float4* __restrict__ p = (const float4*)part + i;
#pragma unroll 16
    for (int ks = 0; ks < 64; ++ks) {
        const float4 v = p[(size_t)ks * (BATCH * NEMB / 4)];
        s.x += v.x; s.y += v.y; s.z += v.z; s.w += v.w;
    }
    const int c = (i * 4) & (NEMB - 1);
    s.x = fmaxf(s.x + bfc[c + 0], 0.f);
    s.y = fmaxf(s.y + bfc[c + 1], 0.f);
    s.z = fmaxf(s.z + bfc[c + 2], 0.f);
    s.w = fmaxf(s.w + bfc[c + 3], 0.f);
    ((float4*)out)[i] = s;
}

__global__ void bias_relu_kernel(float* __restrict__ out, const float* __restrict__ bfc) {
    const int i = blockIdx.x * 256 + threadIdx.x;
    float4 v = ((float4*)out)[i];
    const int c = (i * 4) & (NEMB - 1);
    v.x = fmaxf(v.x + bfc[c + 0], 0.f);
    v.y = fmaxf(v.y + bfc[c + 1], 0.f);
    v.z = fmaxf(v.z + bfc[c + 2], 0.f);
    v.w = fmaxf(v.w + bfc[c + 3], 0.f);
    ((float4*)out)[i] = v;
}

// ---------------------------------------------------------------------------
// Legacy fallback (round-2 kernel, known-pass) if d_ws is too small.
// ---------------------------------------------------------------------------
__global__ __launch_bounds__(512, 2) void fused_legacy_kernel(
    const float* __restrict__ ctx, const float* __restrict__ Wrel,
    const float* __restrict__ brel, const float* __restrict__ Wfc,
    float* __restrict__ out)
{
    const int bid = blockIdx.x;
    const int ks  = bid & 31;
    const int mb  = bid >> 5;
    const int tid = threadIdx.x;
    const int w   = tid >> 6;
    const int l   = tid & 63;
    const int l15 = l & 15;
    const int kb  = l >> 4;

    __shared__ unsigned short h_lds[2][128 * NHID];
    __shared__ int pair_i[63], pair_j[63];

    if (tid < 63) {
        int rem = ks * 63 + tid;
        int i = 0;
        while (rem >= (NUM_ENT - 1 - i)) { rem -= (NUM_ENT - 1 - i); ++i; }
        pair_i[tid] = i;
        pair_j[tid] = i + 1 + rem;
    }

    bf16x8 bw[4];
    float  brl[4];
#pragma unroll
    for (int ns = 0; ns < 4; ++ns) {
        const int n = l15 + 16 * ns;
#pragma unroll
        for (int e = 0; e < 8; ++e) {
            const int k = kb * 8 + e;
            bw[ns][e] = (short)f2bf((k < 16) ? Wrel[k * NHID + n] : 0.f);
        }
        brl[ns] = brel[n];
    }
    __syncthreads();

    f32x4 acc[8][2];
#pragma unroll
    for (int m = 0; m < 8; ++m)
#pragma unroll
        for (int n = 0; n < 2; ++n) acc[m][n] = (f32x4){0.f, 0.f, 0.f, 0.f};

    const int row_h = mb * 128 + w * 16 + l15;
    const float* __restrict__ ctx_row = ctx + (size_t)row_h * (NUM_ENT * DIM_ENT);

    for (int r = 0; r < 63; ++r) {
        unsigned short* __restrict__ hb = &h_lds[r & 1][0];
        bf16x8 ah = {0, 0, 0, 0, 0, 0, 0, 0};
        if (kb < 2) {
            const int ent = (kb == 0) ? pair_i[r] : pair_j[r];
            const float4 v0 = *(const float4*)(ctx_row + ent * DIM_ENT);
            const float4 v1 = *(const float4*)(ctx_row + ent * DIM_ENT + 4);
            ah[0] = (short)f2bf(v0.x); ah[1] = (short)f2bf(v0.y);
            ah[2] = (short)f2bf(v0.z); ah[3] = (short)f2bf(v0.w);
            ah[4] = (short)f2bf(v1.x); ah[5] = (short)f2bf(v1.y);
            ah[6] = (short)f2bf(v1.z); ah[7] = (short)f2bf(v1.w);
        }
#pragma unroll
        for (int ns = 0; ns < 4; ++ns) {
            f32x4 c = {0.f, 0.f, 0.f, 0.f};
            c = __builtin_amdgcn_mfma_f32_16x16x32_bf16(ah, bw[ns], c, 0, 0, 0);
#pragma unroll
            for (int reg = 0; reg < 4; ++reg) {
                float hv = c[reg] + brl[ns];
                hv = hv > 0.f ? hv : 0.f;
                const int rr = w * 16 + kb * 4 + reg;
                const int cc = l15 + 16 * ns;
                int byte = (rr * NHID + cc) * 2;
                byte ^= ((rr & 7) << 4);
                *(unsigned short*)((char*)hb + byte) = f2bf(hv);
            }
        }
        __syncthreads();

        const float* __restrict__ wf = Wfc + (size_t)(ks * 63 + r) * NHID * NEMB;
#pragma unroll
        for (int kh = 0; kh < 2; ++kh) {
            bf16x8 bb[2];
#pragma unroll
            for (int ns = 0; ns < 2; ++ns) {
                const int n = w * 32 + ns * 16 + l15;
                const float* __restrict__ col = wf + (size_t)(kh * 32 + kb * 8) * NEMB + n;
#pragma unroll
                for (int e = 0; e < 8; ++e) bb[ns][e] = (short)f2bf(col[(size_t)e * NEMB]);
            }
#pragma unroll
            for (int m = 0; m < 8; ++m) {
                const int rr = m * 16 + l15;
                int byte = (rr * NHID + kh * 32 + kb * 8) * 2;
                byte ^= ((rr & 7) << 4);
                const bf16x8 aa = *(const bf16x8*)((const char*)hb + byte);
                acc[m][0] = __builtin_amdgcn_mfma_f32_16x16x32_bf16(aa, bb[0], acc[m][0], 0, 0, 0);
                acc[m][1] = __builtin_amdgcn_mfma_f32_16x16x32_bf16(aa, bb[1], acc[m][1], 0, 0, 0);
            }
        }
    }
#pragma unroll
    for (int m = 0; m < 8; ++m)
#pragma unroll
        for (int ns = 0; ns < 2; ++ns)
#pragma unroll
            for (int reg = 0; reg < 4; ++reg) {
                const int row = mb * 128 + m * 16 + kb * 4 + reg;
                const int col = w * 32 + ns * 16 + l15;
                atomicAdd(&out[(size_t)row * NEMB + col], acc[m][ns][reg]);
            }
}

extern "C" void kernel_launch(void* const* d_in, const int* in_sizes, int n_in,
                              void* d_out, int out_size, void* d_ws, size_t ws_size,
                              hipStream_t stream) {
    const float* ctx  = (const float*)d_in[0];
    const float* Wrel = (const float*)d_in[1];
    const float* brel = (const float*)d_in[2];
    const float* Wfc  = (const float*)d_in[3];
    const float* bfc  = (const float*)d_in[4];
    float* out = (float*)d_out;

    const size_t CTXB = (size_t)BATCH * NUM_ENT * DIM_ENT * 2;   // 1 MiB
    const size_t WFCB = (size_t)KTOT * NEMB * 2;                 // 63 MiB
    const size_t PART = (size_t)64 * BATCH * NEMB * 4;           // 64 MiB
    unsigned short* ctxb = (unsigned short*)d_ws;
    unsigned short* wfcb = (unsigned short*)((char*)d_ws + CTXB);
    float*          part = (float*)((char*)d_ws + CTXB + WFCB);

    if (ws_size >= CTXB + WFCB + PART) {
        prep_ctx_kernel<<<256, 256, 0, stream>>>(ctx, ctxb);
        prep_wfc2_kernel<<<NUM_REL, 512, 0, stream>>>(Wfc, wfcb);
        fused4_kernel<false><<<512, 512, 0, stream>>>(ctxb, Wrel, brel, wfcb, part);
        reduce_kernel<<<256, 256, 0, stream>>>(part, bfc, out);
    } else if (ws_size >= CTXB + WFCB) {
        prep_ctx_kernel<<<256, 256, 0, stream>>>(ctx, ctxb);
        prep_wfc2_kernel<<<NUM_REL, 512, 0, stream>>>(Wfc, wfcb);
        hipMemsetAsync(out, 0, (size_t)BATCH * NEMB * sizeof(float), stream);
        fused4_kernel<true><<<512, 512, 0, stream>>>(ctxb, Wrel, brel, wfcb, out);
        bias_relu_kernel<<<(BATCH * NEMB / 4) / 256, 256, 0, stream>>>(out, bfc);
    } else {
        hipMemsetAsync(out, 0, (size_t)BATCH * NEMB * sizeof(float), stream);
        fused_legacy_kernel<<<256, 512, 0, stream>>>(ctx, Wrel, brel, Wfc, out);
        bias_relu_kernel<<<(BATCH * NEMB / 4) / 256, 256, 0, stream>>>(out, bfc);
    }
}

// Round 6
// 306.826 us; speedup vs baseline: 1.7849x; 1.6496x over previous
//
#include <hip/hip_runtime.h>

#define NUM_ENT 64
#define DIM_ENT 8
#define NHID    64
#define NEMB    256
#define BATCH   1024
#define NUM_REL 2016
#define KTOT    (NUM_REL * NHID)   // 129024
#define NSLICE  64

typedef __attribute__((ext_vector_type(8))) short bf16x8;
typedef __attribute__((ext_vector_type(4))) float f32x4;

#define AS1 __attribute__((address_space(1)))
#define AS3 __attribute__((address_space(3)))

__device__ __forceinline__ unsigned short f2bf(float f) {
    union { float f; unsigned u; } v; v.f = f;
    unsigned r = v.u + 0x7FFF + ((v.u >> 16) & 1);   // RNE
    return (unsigned short)(r >> 16);
}

__device__ __forceinline__ void gll16(const void* g, void* l) {
    __builtin_amdgcn_global_load_lds((const AS1 unsigned int*)g,
                                     (AS3 unsigned int*)l, 16, 0, 0);
}
__device__ __forceinline__ unsigned lds_b(const void* p) {
    return (unsigned)(size_t)(const AS3 char*)p;
}

// ---------------------------------------------------------------------------
// prep: ctx fp32 [1024,512] -> bf16 (coalesced)
// ---------------------------------------------------------------------------
__global__ void prep_ctx_kernel(const float* __restrict__ ctx,
                                unsigned short* __restrict__ ctxb) {
    const int id = blockIdx.x * 256 + threadIdx.x;
    const float4 a = ((const float4*)ctx)[id * 2];
    const float4 b = ((const float4*)ctx)[id * 2 + 1];
    bf16x8 v;
    v[0] = (short)f2bf(a.x); v[1] = (short)f2bf(a.y);
    v[2] = (short)f2bf(a.z); v[3] = (short)f2bf(a.w);
    v[4] = (short)f2bf(b.x); v[5] = (short)f2bf(b.y);
    v[6] = (short)f2bf(b.z); v[7] = (short)f2bf(b.w);
    *(bf16x8*)(ctxb + (size_t)id * 8) = v;
}

// ---------------------------------------------------------------------------
// prep: Wfc fp32 [129024,256] -> frag-linear bf16, one relation per block.
//   u16 index = ((g*2+kh)*16 + fid)*512 + l*8 + e
//     holds Wfc[g*64 + kh*32 + (l>>4)*8 + e][(fid>>1)*32 + (fid&1)*16 + (l&15)]
// ---------------------------------------------------------------------------
__global__ __launch_bounds__(512) void prep_wfc2_kernel(
    const float* __restrict__ Wfc, unsigned short* __restrict__ wfcb) {
    __shared__ unsigned short tile[64 * 260];          // pad 256->260
    const int g = blockIdx.x;                          // 0..2015
    const int t = threadIdx.x;
    const float4* __restrict__ src = (const float4*)(Wfc + (size_t)g * 64 * NEMB);
#pragma unroll
    for (int i = 0; i < 8; ++i) {
        const int f4 = t + i * 512;
        const float4 v = src[f4];
        const int f = f4 * 4, k = f >> 8, n = f & 255;
        ushort4 u;
        u.x = f2bf(v.x); u.y = f2bf(v.y); u.z = f2bf(v.z); u.w = f2bf(v.w);
        *(ushort4*)&tile[k * 260 + n] = u;
    }
    __syncthreads();
    unsigned short* __restrict__ dst = wfcb + (size_t)g * 16384 + (size_t)t * 32;
#pragma unroll
    for (int c = 0; c < 4; ++c) {
        const int s   = t * 4 + c;                     // slot 0..2047
        const int l   = s & 63;
        const int fid = (s >> 6) & 15;
        const int kh  = s >> 10;
        const int n   = (fid >> 1) * 32 + (fid & 1) * 16 + (l & 15);
        const int k0  = kh * 32 + ((l >> 4) << 3);
        bf16x8 v;
#pragma unroll
        for (int e = 0; e < 8; ++e) v[e] = (short)tile[(k0 + e) * 260 + n];
        *(bf16x8*)(dst + c * 8) = v;
    }
}

// ---------------------------------------------------------------------------
// fused5: BM=256, 1 block/CU, B via global_load_lds double-buffer with
// counted vmcnt(6); h single-buffer; 2 barriers/relation; no spills.
// ---------------------------------------------------------------------------
template<bool ATOMIC>
__global__ __launch_bounds__(512, 2) void fused5_kernel(
    const unsigned short* __restrict__ ctxb,   // [1024,512] bf16
    const float*          __restrict__ Wrel,   // [16,64]
    const float*          __restrict__ brel,   // [64]
    const unsigned short* __restrict__ wfcb,   // frag-linear bf16
    float*                __restrict__ outp)   // partial[64][1024,256] or out
{
    const int bid = blockIdx.x;                       // 0..255
    const int mb  = (bid >> 3) & 3;                   // m-tile 0..3 (256 rows)
    const int ks  = (bid & 7) + 8 * (bid >> 5);       // slice 0..63; sharers same XCD
    const int start = (ks < 32) ? ks * 32 : 1024 + (ks - 32) * 31;
    const int cnt   = (ks < 32) ? 32 : 31;

    const int tid = threadIdx.x;
    const int w   = tid >> 6;            // wave 0..7
    const int l   = tid & 63;
    const int l15 = l & 15;
    const int kb  = l >> 4;
    const int wm  = w >> 2;              // 0..1  (row half: 128 rows)
    const int wc  = w & 3;               // 0..3  (col strip: 64 cols)

    __shared__ unsigned short h_lds[256 * NHID];      // 32 KB (XOR-swizzled rows)
    __shared__ unsigned short b_lds[2][16384];        // 2 x 32 KB, frag-linear
    __shared__ int pair_i[32], pair_j[32];

    if (tid < cnt) {
        int rem = start + tid;
        int i = 0;
        while (rem >= (NUM_ENT - 1 - i)) { rem -= (NUM_ENT - 1 - i); ++i; }
        pair_i[tid] = i;
        pair_j[tid] = i + 1 + rem;
    }

    // Wrel^T A-frag for swapped phase-1; padding row k==16 carries the bias.
    bf16x8 bw[4];
#pragma unroll
    for (int ns = 0; ns < 4; ++ns) {
#pragma unroll
        for (int e = 0; e < 8; ++e) {
            const int k = kb * 8 + e;
            float v = 0.f;
            if (k < 16)       v = Wrel[k * NHID + ns * 16 + l15];
            else if (k == 16) v = brel[ns * 16 + l15];
            bw[ns][e] = (short)f2bf(v);
        }
    }

    __syncthreads();   // pair table ready

    f32x4 acc[8][4];
#pragma unroll
    for (int m = 0; m < 8; ++m)
#pragma unroll
        for (int n = 0; n < 4; ++n) acc[m][n] = (f32x4){0.f, 0.f, 0.f, 0.f};

    // phase-1: wave w computes rows w*32 .. w*32+31 (2 groups of 16)
    const unsigned short* __restrict__ ctx_g0 =
        ctxb + (size_t)(mb * 256 + w * 32 + l15) * (NUM_ENT * DIM_ENT);
    const unsigned short* __restrict__ ctx_g1 = ctx_g0 + 16 * (NUM_ENT * DIM_ENT);

    bf16x8 ahc[2], ahn[2];
    {
        bf16x8 z = {0, 0, 0, 0, 0, 0, 0, 0};
        if (kb == 2) z[0] = (short)0x3F80;   // 1.0 -> bias row (k==16)
        ahc[0] = ahc[1] = ahn[0] = ahn[1] = z;
        if (kb < 2) {                         // preload relation 'start'
            const int e0 = (kb == 0) ? pair_i[0] : pair_j[0];
            ahc[0] = *(const bf16x8*)(ctx_g0 + e0 * DIM_ENT);
            ahc[1] = *(const bf16x8*)(ctx_g1 + e0 * DIM_ENT);
        }
    }

    // B staging: per relation 32 KB frag-linear; 4 x 16B per thread
    auto ISSUE_B = [&](int g, int buf) {
        const unsigned short* __restrict__ src =
            wfcb + (size_t)g * 16384 + (size_t)(w * 64 + l) * 8;
        unsigned short* dst = &b_lds[buf][(size_t)w * 512];
#pragma unroll
        for (int c = 0; c < 4; ++c)
            gll16(src + c * 4096, dst + c * 4096);
    };

    ISSUE_B(start, 0);

    for (int r = 0; r < cnt; ++r) {
        const int rn = (r + 1 < cnt) ? r + 1 : r;

        // A: prefetch next relation's ctx pair (oldest vmem -> counted wait later)
        if (kb < 2) {
            const int en = (kb == 0) ? pair_i[rn] : pair_j[rn];
            ahn[0] = *(const bf16x8*)(ctx_g0 + en * DIM_ENT);
            ahn[1] = *(const bf16x8*)(ctx_g1 + en * DIM_ENT);
        }

        // B: phase-1 — h = relu(pairs @ Wrel + b) for 32 rows, write to h_lds
#pragma unroll
        for (int grp = 0; grp < 2; ++grp) {
            const int rw = w * 32 + grp * 16 + l15;
#pragma unroll
            for (int ns = 0; ns < 4; ++ns) {
                f32x4 c = {0.f, 0.f, 0.f, 0.f};
                c = __builtin_amdgcn_mfma_f32_16x16x32_bf16(bw[ns], ahc[grp], c, 0, 0, 0);
                ushort4 u;
                u.x = f2bf(fmaxf(c[0], 0.f));
                u.y = f2bf(fmaxf(c[1], 0.f));
                u.z = f2bf(fmaxf(c[2], 0.f));
                u.w = f2bf(fmaxf(c[3], 0.f));
                int byte = (rw * NHID + ns * 16 + kb * 4) * 2;
                byte ^= ((rw & 7) << 4);
                *(ushort4*)((char*)h_lds + byte) = u;   // ds_write_b64
            }
        }

        // C: issue next B tile into the other buffer (stays in flight)
        ISSUE_B(start + rn, (r + 1) & 1);

        // D/E: drain THIS relation's B loads only (6 newer stay in flight)
        asm volatile("s_waitcnt vmcnt(6)" ::: "memory");
        asm volatile("s_waitcnt lgkmcnt(0)" ::: "memory");
        __builtin_amdgcn_s_barrier();
        __builtin_amdgcn_sched_barrier(0);

        // F: phase-2 — acc += h[256,64] @ B[64,256]
        {
            const char* hb = (const char*)h_lds;
            const unsigned bbase = lds_b(&b_lds[r & 1][0]);
#pragma unroll
            for (int kh = 0; kh < 2; ++kh) {
                bf16x8 bb0, bb1, bb2, bb3;
                const unsigned a0 = bbase + (unsigned)(((kh * 16 + wc * 4) * 512 + l * 8) * 2);
                asm volatile("ds_read_b128 %0, %1"             : "=v"(bb0) : "v"(a0));
                asm volatile("ds_read_b128 %0, %1 offset:1024" : "=v"(bb1) : "v"(a0));
                asm volatile("ds_read_b128 %0, %1 offset:2048" : "=v"(bb2) : "v"(a0));
                asm volatile("ds_read_b128 %0, %1 offset:3072" : "=v"(bb3) : "v"(a0));
                asm volatile("s_waitcnt lgkmcnt(0)" ::: "memory");
                __builtin_amdgcn_sched_barrier(0);
#pragma unroll
                for (int m = 0; m < 8; ++m) {
                    const int rr = wm * 128 + m * 16 + l15;
                    int byte = (rr * NHID + kh * 32 + kb * 8) * 2;
                    byte ^= ((rr & 7) << 4);
                    const bf16x8 aa = *(const bf16x8*)(hb + byte);
                    acc[m][0] = __builtin_amdgcn_mfma_f32_16x16x32_bf16(aa, bb0, acc[m][0], 0, 0, 0);
                    acc[m][1] = __builtin_amdgcn_mfma_f32_16x16x32_bf16(aa, bb1, acc[m][1], 0, 0, 0);
                    acc[m][2] = __builtin_amdgcn_mfma_f32_16x16x32_bf16(aa, bb2, acc[m][2], 0, 0, 0);
                    acc[m][3] = __builtin_amdgcn_mfma_f32_16x16x32_bf16(aa, bb3, acc[m][3], 0, 0, 0);
                }
            }
        }

        // G: protect h (single-buffered) and recycled B buffer
        asm volatile("s_waitcnt lgkmcnt(0)" ::: "memory");
        __builtin_amdgcn_s_barrier();
        __builtin_amdgcn_sched_barrier(0);

        ahc[0] = ahn[0]; ahc[1] = ahn[1];
    }

    // epilogue
    float* __restrict__ dst = ATOMIC ? outp : (outp + (size_t)ks * BATCH * NEMB);
#pragma unroll
    for (int m = 0; m < 8; ++m)
#pragma unroll
        for (int nf = 0; nf < 4; ++nf) {
            const int col = wc * 64 + (nf >> 1) * 32 + (nf & 1) * 16 + l15;
#pragma unroll
            for (int reg = 0; reg < 4; ++reg) {
                const int row = mb * 256 + wm * 128 + m * 16 + kb * 4 + reg;
                if (ATOMIC) atomicAdd(&dst[(size_t)row * NEMB + col], acc[m][nf][reg]);
                else        dst[(size_t)row * NEMB + col] = acc[m][nf][reg];
            }
        }
}

// partial[64][1024,256] -> out = relu(sum + bias)
__global__ void reduce_kernel(const float* __restrict__ part,
                              const float* __restrict__ bfc,
                              float* __restrict__ out) {
    const int i = blockIdx.x * 256 + threadIdx.x;
    float4 s = {0.f, 0.f, 0.f, 0.f};
    const float4* __restrict__ p = (const float4*)part + i;
#pragma unroll 16
    for (int ks = 0; ks < NSLICE; ++ks) {
        const float4 v = p[(size_t)ks * (BATCH * NEMB / 4)];
        s.x += v.x; s.y += v.y; s.z += v.z; s.w += v.w;
    }
    const int c = (i * 4) & (NEMB - 1);
    s.x = fmaxf(s.x + bfc[c + 0], 0.f);
    s.y = fmaxf(s.y + bfc[c + 1], 0.f);
    s.z = fmaxf(s.z + bfc[c + 2], 0.f);
    s.w = fmaxf(s.w + bfc[c + 3], 0.f);
    ((float4*)out)[i] = s;
}

__global__ void bias_relu_kernel(float* __restrict__ out, const float* __restrict__ bfc) {
    const int i = blockIdx.x * 256 + threadIdx.x;
    float4 v = ((float4*)out)[i];
    const int c = (i * 4) & (NEMB - 1);
    v.x = fmaxf(v.x + bfc[c + 0], 0.f);
    v.y = fmaxf(v.y + bfc[c + 1], 0.f);
    v.z = fmaxf(v.z + bfc[c + 2], 0.f);
    v.w = fmaxf(v.w + bfc[c + 3], 0.f);
    ((float4*)out)[i] = v;
}

// ---------------------------------------------------------------------------
// Legacy fallback (round-2 kernel, known-pass) if d_ws is too small.
// ---------------------------------------------------------------------------
__global__ __launch_bounds__(512, 2) void fused_legacy_kernel(
    const float* __restrict__ ctx, const float* __restrict__ Wrel,
    const float* __restrict__ brel, const float* __restrict__ Wfc,
    float* __restrict__ out)
{
    const int bid = blockIdx.x;
    const int ks  = bid & 31;
    const int mb  = bid >> 5;
    const int tid = threadIdx.x;
    const int w   = tid >> 6;
    const int l   = tid & 63;
    const int l15 = l & 15;
    const int kb  = l >> 4;

    __shared__ unsigned short h_lds[2][128 * NHID];
    __shared__ int pair_i[63], pair_j[63];

    if (tid < 63) {
        int rem = ks * 63 + tid;
        int i = 0;
        while (rem >= (NUM_ENT - 1 - i)) { rem -= (NUM_ENT - 1 - i); ++i; }
        pair_i[tid] = i;
        pair_j[tid] = i + 1 + rem;
    }

    bf16x8 bw[4];
    float  brl[4];
#pragma unroll
    for (int ns = 0; ns < 4; ++ns) {
        const int n = l15 + 16 * ns;
#pragma unroll
        for (int e = 0; e < 8; ++e) {
            const int k = kb * 8 + e;
            bw[ns][e] = (short)f2bf((k < 16) ? Wrel[k * NHID + n] : 0.f);
        }
        brl[ns] = brel[n];
    }
    __syncthreads();

    f32x4 acc[8][2];
#pragma unroll
    for (int m = 0; m < 8; ++m)
#pragma unroll
        for (int n = 0; n < 2; ++n) acc[m][n] = (f32x4){0.f, 0.f, 0.f, 0.f};

    const int row_h = mb * 128 + w * 16 + l15;
    const float* __restrict__ ctx_row = ctx + (size_t)row_h * (NUM_ENT * DIM_ENT);

    for (int r = 0; r < 63; ++r) {
        unsigned short* __restrict__ hb = &h_lds[r & 1][0];
        bf16x8 ah = {0, 0, 0, 0, 0, 0, 0, 0};
        if (kb < 2) {
            const int ent = (kb == 0) ? pair_i[r] : pair_j[r];
            const float4 v0 = *(const float4*)(ctx_row + ent * DIM_ENT);
            const float4 v1 = *(const float4*)(ctx_row + ent * DIM_ENT + 4);
            ah[0] = (short)f2bf(v0.x); ah[1] = (short)f2bf(v0.y);
            ah[2] = (short)f2bf(v0.z); ah[3] = (short)f2bf(v0.w);
            ah[4] = (short)f2bf(v1.x); ah[5] = (short)f2bf(v1.y);
            ah[6] = (short)f2bf(v1.z); ah[7] = (short)f2bf(v1.w);
        }
#pragma unroll
        for (int ns = 0; ns < 4; ++ns) {
            f32x4 c = {0.f, 0.f, 0.f, 0.f};
            c = __builtin_amdgcn_mfma_f32_16x16x32_bf16(ah, bw[ns], c, 0, 0, 0);
#pragma unroll
            for (int reg = 0; reg < 4; ++reg) {
                float hv = c[reg] + brl[ns];
                hv = hv > 0.f ? hv : 0.f;
                const int rr = w * 16 + kb * 4 + reg;
                const int cc = l15 + 16 * ns;
                int byte = (rr * NHID + cc) * 2;
                byte ^= ((rr & 7) << 4);
                *(unsigned short*)((char*)hb + byte) = f2bf(hv);
            }
        }
        __syncthreads();

        const float* __restrict__ wf = Wfc + (size_t)(ks * 63 + r) * NHID * NEMB;
#pragma unroll
        for (int kh = 0; kh < 2; ++kh) {
            bf16x8 bb[2];
#pragma unroll
            for (int ns = 0; ns < 2; ++ns) {
                const int n = w * 32 + ns * 16 + l15;
                const float* __restrict__ col = wf + (size_t)(kh * 32 + kb * 8) * NEMB + n;
#pragma unroll
                for (int e = 0; e < 8; ++e) bb[ns][e] = (short)f2bf(col[(size_t)e * NEMB]);
            }
#pragma unroll
            for (int m = 0; m < 8; ++m) {
                const int rr = m * 16 + l15;
                int byte = (rr * NHID + kh * 32 + kb * 8) * 2;
                byte ^= ((rr & 7) << 4);
                const bf16x8 aa = *(const bf16x8*)((const char*)hb + byte);
                acc[m][0] = __builtin_amdgcn_mfma_f32_16x16x32_bf16(aa, bb[0], acc[m][0], 0, 0, 0);
                acc[m][1] = __builtin_amdgcn_mfma_f32_16x16x32_bf16(aa, bb[1], acc[m][1], 0, 0, 0);
            }
        }
    }
#pragma unroll
    for (int m = 0; m < 8; ++m)
#pragma unroll
        for (int ns = 0; ns < 2; ++ns)
#pragma unroll
            for (int reg = 0; reg < 4; ++reg) {
                const int row = mb * 128 + m * 16 + kb * 4 + reg;
                const int col = w * 32 + ns * 16 + l15;
                atomicAdd(&out[(size_t)row * NEMB + col], acc[m][ns][reg]);
            }
}

extern "C" void kernel_launch(void* const* d_in, const int* in_sizes, int n_in,
                              void* d_out, int out_size, void* d_ws, size_t ws_size,
                              hipStream_t stream) {
    const float* ctx  = (const float*)d_in[0];
    const float* Wrel = (const float*)d_in[1];
    const float* brel = (const float*)d_in[2];
    const float* Wfc  = (const float*)d_in[3];
    const float* bfc  = (const float*)d_in[4];
    float* out = (float*)d_out;

    const size_t CTXB = (size_t)BATCH * NUM_ENT * DIM_ENT * 2;   // 1 MiB
    const size_t WFCB = (size_t)KTOT * NEMB * 2;                 // 63 MiB
    const size_t PART = (size_t)NSLICE * BATCH * NEMB * 4;       // 64 MiB
    unsigned short* ctxb = (unsigned short*)d_ws;
    unsigned short* wfcb = (unsigned short*)((char*)d_ws + CTXB);
    float*          part = (float*)((char*)d_ws + CTXB + WFCB);

    if (ws_size >= CTXB + WFCB + PART) {
        prep_ctx_kernel<<<256, 256, 0, stream>>>(ctx, ctxb);
        prep_wfc2_kernel<<<NUM_REL, 512, 0, stream>>>(Wfc, wfcb);
        fused5_kernel<false><<<256, 512, 0, stream>>>(ctxb, Wrel, brel, wfcb, part);
        reduce_kernel<<<256, 256, 0, stream>>>(part, bfc, out);
    } else if (ws_size >= CTXB + WFCB) {
        prep_ctx_kernel<<<256, 256, 0, stream>>>(ctx, ctxb);
        prep_wfc2_kernel<<<NUM_REL, 512, 0, stream>>>(Wfc, wfcb);
        hipMemsetAsync(out, 0, (size_t)BATCH * NEMB * sizeof(float), stream);
        fused5_kernel<true><<<256, 512, 0, stream>>>(ctxb, Wrel, brel, wfcb, out);
        bias_relu_kernel<<<(BATCH * NEMB / 4) / 256, 256, 0, stream>>>(out, bfc);
    } else {
        hipMemsetAsync(out, 0, (size_t)BATCH * NEMB * sizeof(float), stream);
        fused_legacy_kernel<<<256, 512, 0, stream>>>(ctx, Wrel, brel, Wfc, out);
        bias_relu_kernel<<<(BATCH * NEMB / 4) / 256, 256, 0, stream>>>(out, bfc);
    }
}